// Round 9
// baseline (375.477 us; speedup 1.0000x reference)
//
#include <hip/hip_runtime.h>
#include <hip/hip_bf16.h>

#define LL 4096
#define DD 192
#define NN 16
#define NCH 64      // chunks for the 2-pass scan
#define LC  64      // steps per chunk = LL/NCH

typedef float v2f __attribute__((ext_vector_type(2)));
typedef float f32x4 __attribute__((ext_vector_type(4)));
typedef short bf16x8 __attribute__((ext_vector_type(8)));   // 8 bf16 in 4 VGPRs

__device__ __forceinline__ v2f v2(float a, float b) { v2f r; r.x = a; r.y = b; return r; }
__device__ __forceinline__ float fexp2(float x) { return __builtin_amdgcn_exp2f(x); }

// ---------------------------------------------------------------------------
// K0: weight repack for the MFMA projection (unchanged from R8).
// ---------------------------------------------------------------------------
__global__ __launch_bounds__(192) void k_wprep(
    const float* __restrict__ Wp, __hip_bfloat16* __restrict__ Whi,
    __hip_bfloat16* __restrict__ Wlo)
{
  const int d = threadIdx.x;
  const int r = blockIdx.x;
  const int k = r / 48, cc = r % 48;
  float v = 0.f;
  if      (cc < 6)               v = Wp[((size_t)k * 38 + cc) * DD + d];
  else if (cc >= 8  && cc < 24)  v = Wp[((size_t)k * 38 + 6  + (cc - 8))  * DD + d];
  else if (cc >= 24 && cc < 40)  v = Wp[((size_t)k * 38 + 22 + (cc - 24)) * DD + d];
  const __hip_bfloat16 hi = __float2bfloat16(v);
  Whi[(size_t)r * DD + d] = hi;
  Wlo[(size_t)r * DD + d] = __float2bfloat16(v - __bfloat162float(hi));
}

// ---------------------------------------------------------------------------
// K2: tiled transpose x[b,d,p] -> xh (bf16 hi) + xl (residual) (unchanged).
// ---------------------------------------------------------------------------
__global__ __launch_bounds__(256) void k_xt(
    const float* __restrict__ x, __hip_bfloat16* __restrict__ xh,
    __hip_bfloat16* __restrict__ xl)
{
  __shared__ float tile[64][65];
  const int b = blockIdx.z, d0 = blockIdx.y * 64, p0 = blockIdx.x * 64;
  const int tx = threadIdx.x & 63, ty = threadIdx.x >> 6;
#pragma unroll
  for (int r = ty; r < 64; r += 4)
    tile[r][tx] = x[((size_t)b * DD + d0 + r) * LL + p0 + tx];
  __syncthreads();
#pragma unroll
  for (int pr = ty; pr < 64; pr += 4) {
    const float vv = tile[tx][pr];
    const __hip_bfloat16 hi = __float2bfloat16(vv);
    const size_t idx = ((size_t)b * LL + p0 + pr) * DD + d0 + tx;
    xh[idx] = hi;
    xl[idx] = __float2bfloat16(vv - __bfloat162float(hi));
  }
}

// ---------------------------------------------------------------------------
// K1: MFMA projection (unchanged from R8).
// ---------------------------------------------------------------------------
__global__ __launch_bounds__(192) void k_mfproj(
    const __hip_bfloat16* __restrict__ xh, const __hip_bfloat16* __restrict__ xl,
    const __hip_bfloat16* __restrict__ Whi, const __hip_bfloat16* __restrict__ Wlo,
    float* __restrict__ dtr, float* __restrict__ Bsv, float* __restrict__ Csv)
{
  const int tid  = threadIdx.x;
  const int w    = tid >> 6;          // wave 0..2
  const int lane = tid & 63;
  const int n    = lane & 15;
  const int quad = lane >> 4;
  const int p0   = blockIdx.x * 16;
  const int b    = blockIdx.y;
  const int p    = p0 + n;

  const short* __restrict__ xhp = (const short*)xh + ((size_t)b * LL + p) * DD + quad * 8;
  const short* __restrict__ xlp = (const short*)xl + ((size_t)b * LL + p) * DD + quad * 8;
  const short* __restrict__ whp = (const short*)Whi + ((size_t)(w * 4) * 16 + n) * DD + quad * 8;
  const short* __restrict__ wlp = (const short*)Wlo + ((size_t)(w * 4) * 16 + n) * DD + quad * 8;

  f32x4 acc[4];
#pragma unroll
  for (int m = 0; m < 4; ++m) acc[m] = (f32x4){0.f, 0.f, 0.f, 0.f};

#pragma unroll
  for (int ks = 0; ks < 6; ++ks) {
    const bf16x8 bh = *(const bf16x8*)(xhp + ks * 32);
    const bf16x8 bl = *(const bf16x8*)(xlp + ks * 32);
#pragma unroll
    for (int m = 0; m < 4; ++m) {
      const bf16x8 ah = *(const bf16x8*)(whp + (size_t)m * 16 * DD + ks * 32);
      const bf16x8 al = *(const bf16x8*)(wlp + (size_t)m * 16 * DD + ks * 32);
      acc[m] = __builtin_amdgcn_mfma_f32_16x16x32_bf16(ah, bh, acc[m], 0, 0, 0);
      acc[m] = __builtin_amdgcn_mfma_f32_16x16x32_bf16(ah, bl, acc[m], 0, 0, 0);
      acc[m] = __builtin_amdgcn_mfma_f32_16x16x32_bf16(al, bh, acc[m], 0, 0, 0);
    }
  }

  const int sg = ((p & 63) << 6) | (p >> 6);     // sigma(p)
  int lsv[4] = { p, sg, LL - 1 - p, LL - 1 - sg };

#pragma unroll
  for (int m = 0; m < 4; ++m) {
    const int mt = w * 4 + m;
    const int k  = mt / 3;                        // direction
    const int t  = mt - k * 3;                    // tile within direction
    const int cc0 = t * 16 + quad * 4;            // packed channel of reg 0
    const size_t rowb = (size_t)(b * 4 + k) * LL + lsv[k];
    const float4 vv = make_float4(acc[m][0], acc[m][1], acc[m][2], acc[m][3]);
    if      (cc0 < 8)  *(float4*)(dtr + rowb * 8  + cc0)        = vv;
    else if (cc0 < 24) *(float4*)(Bsv + rowb * 16 + (cc0 - 8))  = vv;
    else if (cc0 < 40) *(float4*)(Csv + rowb * 16 + (cc0 - 24)) = vv;
  }
}

// u-row index for scan position l of direction k.
__device__ __forceinline__ int urow(int l, bool rev, bool trans) {
  const int rl = rev ? (LL - 1 - l) : l;
  return trans ? (((rl & 63) << 6) | (rl >> 6)) : rl;
}

// ---------------------------------------------------------------------------
// K3 (pass A): per-chunk scan summaries. NEW: the chunk's dtr/B rows are
// staged into LDS once (coalesced float4), per-step reads become same-address
// LDS broadcasts -> kills the per-iteration L2 round-trip stall.
// ---------------------------------------------------------------------------
__global__ __launch_bounds__(192) void k_partial(
    const float* __restrict__ dtr, const float* __restrict__ Bsv,
    const __hip_bfloat16* __restrict__ xt,
    const float* __restrict__ dtw, const float* __restrict__ dtb,
    const float* __restrict__ Alog,
    __hip_bfloat16* __restrict__ Pv, __hip_bfloat16* __restrict__ qv)
{
  __shared__ float smem[LC * 8 + LC * 16];        // sdt[512] | sB[1024]
  float* __restrict__ sdt = smem;
  float* __restrict__ sB  = smem + LC * 8;

  const int tid = threadIdx.x;
  const int d  = tid;
  const int bk = blockIdx.x;
  const int c  = blockIdx.y;
  const int k = bk & 3, b = bk >> 2;
  const int kd = k * DD + d;
  const bool rev = (k >= 2), trans = (k & 1);
  const float L2E = 1.4426950408889634f;
  const int l0 = c * LC;

  // ---- stage chunk rows: dtr 128 float4, B 256 float4 ----
  {
    const float4* __restrict__ gdt = (const float4*)(dtr + ((size_t)bk * LL + l0) * 8);
    const float4* __restrict__ gB  = (const float4*)(Bsv + ((size_t)bk * LL + l0) * 16);
    float4* __restrict__ s4 = (float4*)smem;
    for (int idx = tid; idx < 384; idx += 192)
      s4[idx] = (idx < 128) ? gdt[idx] : gB[idx - 128];
  }

  v2f An2[8];
#pragma unroll
  for (int j = 0; j < 8; ++j)
    An2[j] = v2(-__expf(Alog[(size_t)kd * NN + 2*j])     * L2E,
                -__expf(Alog[(size_t)kd * NN + 2*j + 1]) * L2E);
  const float w0 = dtw[kd*6+0], w1 = dtw[kd*6+1], w2 = dtw[kd*6+2],
              w3 = dtw[kd*6+3], w4 = dtw[kd*6+4], w5 = dtw[kd*6+5];
  const float bias = dtb[kd];
  const __hip_bfloat16* __restrict__ ub = xt + (size_t)b * LL * DD + d;

  v2f P2[8], q2[8];
#pragma unroll
  for (int j = 0; j < 8; ++j) { P2[j] = v2(1.f, 1.f); q2[j] = v2(0.f, 0.f); }

  float uc = __bfloat162float(ub[(size_t)urow(l0, rev, trans) * DD]);
  __syncthreads();

#pragma unroll 2
  for (int i = 0; i < LC; ++i) {
    float un = 0.f;
    if (i + 1 < LC)
      un = __bfloat162float(ub[(size_t)urow(l0 + i + 1, rev, trans) * DD]);
    const float4 r0 = *(const float4*)(sdt + i * 8);
    const float2 r1 = *(const float2*)(sdt + i * 8 + 4);
    const float4 B0 = *(const float4*)(sB + i * 16);
    const float4 B1 = *(const float4*)(sB + i * 16 + 4);
    const float4 B2 = *(const float4*)(sB + i * 16 + 8);
    const float4 B3 = *(const float4*)(sB + i * 16 + 12);
    float v = bias + r0.x*w0 + r0.y*w1 + r0.z*w2 + r0.w*w3 + r1.x*w4 + r1.y*w5;
    const float sp = (v > 20.f) ? v : __logf(1.f + __expf(v));
    const float dbu = sp * uc;
    const v2f sp2  = v2(sp, sp);
    const v2f dbu2 = v2(dbu, dbu);
    const v2f Bv[8] = { v2(B0.x,B0.y), v2(B0.z,B0.w), v2(B1.x,B1.y), v2(B1.z,B1.w),
                        v2(B2.x,B2.y), v2(B2.z,B2.w), v2(B3.x,B3.y), v2(B3.z,B3.w) };
#pragma unroll
    for (int j = 0; j < 8; ++j) {
      const v2f a = sp2 * An2[j];                 // v_pk_mul
      v2f e; e.x = fexp2(a.x); e.y = fexp2(a.y);
      P2[j] = P2[j] * e;                          // v_pk_mul
      q2[j] = __builtin_elementwise_fma(q2[j], e, dbu2 * Bv[j]);  // pk_mul+pk_fma
    }
    uc = un;
  }

  __hip_bfloat16* __restrict__ Pp = Pv + (((size_t)bk * NCH + c) * DD + d) * NN;
  __hip_bfloat16* __restrict__ qp = qv + (((size_t)bk * NCH + c) * DD + d) * NN;
#pragma unroll
  for (int j = 0; j < 8; ++j) {
    Pp[2*j]   = __float2bfloat16(P2[j].x);
    Pp[2*j+1] = __float2bfloat16(P2[j].y);
    qp[2*j]   = __float2bfloat16(q2[j].x);
    qp[2*j+1] = __float2bfloat16(q2[j].y);
  }
}

// ---------------------------------------------------------------------------
// K4 (pass B): combine chunk summaries; h_in[c] overwrites P[c] in place.
// ---------------------------------------------------------------------------
__global__ __launch_bounds__(256) void k_comb(
    __hip_bfloat16* __restrict__ Pv, const __hip_bfloat16* __restrict__ qv)
{
  const int idx = blockIdx.x * 256 + threadIdx.x;
  const int dn = idx % (DD * NN);
  const int bk = idx / (DD * NN);
  const size_t base = (size_t)bk * NCH * DD * NN + dn;
  float h = 0.f;
  for (int c = 0; c < NCH; ++c) {
    const size_t a = base + (size_t)c * DD * NN;
    const float Pc = __bfloat162float(Pv[a]);
    const float qc = __bfloat162float(qv[a]);
    Pv[a] = __float2bfloat16(h);          // hin[c] = h (pre-chunk state)
    h = fmaf(Pc, h, qc);
  }
}

// ---------------------------------------------------------------------------
// K5 (pass C): real scan per chunk seeded with h_in. NEW: dtr/B/C rows staged
// into LDS once per block; per-step reads are LDS broadcasts.
// ---------------------------------------------------------------------------
__global__ __launch_bounds__(192) void k_scanc(
    const float* __restrict__ dtr, const float* __restrict__ Bsv,
    const float* __restrict__ Csv, const __hip_bfloat16* __restrict__ xt,
    const float* __restrict__ dtw, const float* __restrict__ dtb,
    const float* __restrict__ Alog, const __hip_bfloat16* __restrict__ hin,
    __hip_bfloat16* __restrict__ ys)
{
  __shared__ float smem[LC * 8 + 2 * LC * 16];    // sdt[512] | sB[1024] | sC[1024]
  float* __restrict__ sdt = smem;
  float* __restrict__ sB  = smem + LC * 8;
  float* __restrict__ sC  = smem + LC * 8 + LC * 16;

  const int tid = threadIdx.x;
  const int d  = tid;
  const int bk = blockIdx.x;
  const int c  = blockIdx.y;
  const int k = bk & 3, b = bk >> 2;
  const int kd = k * DD + d;
  const bool rev = (k >= 2), trans = (k & 1);
  const float L2E = 1.4426950408889634f;
  const int l0 = c * LC;

  // ---- stage chunk rows: dtr 128, B 256, C 256 float4 ----
  {
    const float4* __restrict__ gdt = (const float4*)(dtr + ((size_t)bk * LL + l0) * 8);
    const float4* __restrict__ gB  = (const float4*)(Bsv + ((size_t)bk * LL + l0) * 16);
    const float4* __restrict__ gC  = (const float4*)(Csv + ((size_t)bk * LL + l0) * 16);
    float4* __restrict__ s4 = (float4*)smem;
    for (int idx = tid; idx < 640; idx += 192) {
      float4 val;
      if      (idx < 128) val = gdt[idx];
      else if (idx < 384) val = gB[idx - 128];
      else                val = gC[idx - 384];
      s4[idx] = val;
    }
  }

  v2f An2[8];
#pragma unroll
  for (int j = 0; j < 8; ++j)
    An2[j] = v2(-__expf(Alog[(size_t)kd * NN + 2*j])     * L2E,
                -__expf(Alog[(size_t)kd * NN + 2*j + 1]) * L2E);
  const float w0 = dtw[kd*6+0], w1 = dtw[kd*6+1], w2 = dtw[kd*6+2],
              w3 = dtw[kd*6+3], w4 = dtw[kd*6+4], w5 = dtw[kd*6+5];
  const float bias = dtb[kd];
  const __hip_bfloat16* __restrict__ ub = xt + (size_t)b * LL * DD + d;
  __hip_bfloat16* __restrict__ yp = ys + (size_t)bk * LL * DD + d;

  v2f h2[8];
  const __hip_bfloat16* __restrict__ hp = hin + (((size_t)bk * NCH + c) * DD + d) * NN;
#pragma unroll
  for (int j = 0; j < 8; ++j)
    h2[j] = v2(__bfloat162float(hp[2*j]), __bfloat162float(hp[2*j+1]));

  int rowc = urow(l0, rev, trans);
  float uc = __bfloat162float(ub[(size_t)rowc * DD]);
  __syncthreads();

#pragma unroll 2
  for (int i = 0; i < LC; ++i) {
    int rown = 0; float un = 0.f;
    if (i + 1 < LC) {
      rown = urow(l0 + i + 1, rev, trans);
      un = __bfloat162float(ub[(size_t)rown * DD]);
    }
    const float4 r0 = *(const float4*)(sdt + i * 8);
    const float2 r1 = *(const float2*)(sdt + i * 8 + 4);
    const float4 B0 = *(const float4*)(sB + i * 16);
    const float4 B1 = *(const float4*)(sB + i * 16 + 4);
    const float4 B2 = *(const float4*)(sB + i * 16 + 8);
    const float4 B3 = *(const float4*)(sB + i * 16 + 12);
    const float4 C0 = *(const float4*)(sC + i * 16);
    const float4 C1 = *(const float4*)(sC + i * 16 + 4);
    const float4 C2 = *(const float4*)(sC + i * 16 + 8);
    const float4 C3 = *(const float4*)(sC + i * 16 + 12);
    float v = bias + r0.x*w0 + r0.y*w1 + r0.z*w2 + r0.w*w3 + r1.x*w4 + r1.y*w5;
    const float sp = (v > 20.f) ? v : __logf(1.f + __expf(v));
    const float dbu = sp * uc;
    const v2f sp2  = v2(sp, sp);
    const v2f dbu2 = v2(dbu, dbu);
    const v2f Bv[8] = { v2(B0.x,B0.y), v2(B0.z,B0.w), v2(B1.x,B1.y), v2(B1.z,B1.w),
                        v2(B2.x,B2.y), v2(B2.z,B2.w), v2(B3.x,B3.y), v2(B3.z,B3.w) };
    const v2f Cv[8] = { v2(C0.x,C0.y), v2(C0.z,C0.w), v2(C1.x,C1.y), v2(C1.z,C1.w),
                        v2(C2.x,C2.y), v2(C2.z,C2.w), v2(C3.x,C3.y), v2(C3.z,C3.w) };
    v2f ya = v2(0.f, 0.f), yb = v2(0.f, 0.f), yc = v2(0.f, 0.f), yd = v2(0.f, 0.f);
#pragma unroll
    for (int j = 0; j < 8; ++j) {
      const v2f a = sp2 * An2[j];
      v2f e; e.x = fexp2(a.x); e.y = fexp2(a.y);
      h2[j] = __builtin_elementwise_fma(h2[j], e, dbu2 * Bv[j]);
      v2f& yacc = (j < 2) ? ya : (j < 4) ? yb : (j < 6) ? yc : yd;
      yacc = __builtin_elementwise_fma(h2[j], Cv[j], yacc);
    }
    const v2f ysum = (ya + yb) + (yc + yd);
    yp[(size_t)rowc * DD] = __float2bfloat16(ysum.x + ysum.y);
    rowc = rown; uc = un;
  }
}

// ---------------------------------------------------------------------------
// K6: merge + D-skip + LayerNorm(192) + channel-last store (unchanged).
// ---------------------------------------------------------------------------
__global__ __launch_bounds__(64) void k_merge(
    const __hip_bfloat16* __restrict__ ys, const float* __restrict__ x,
    const float* __restrict__ Ds, const float* __restrict__ nw,
    const float* __restrict__ nb, float* __restrict__ out)
{
  const int lane = threadIdx.x;
  const int b = blockIdx.y;
  const int p0 = blockIdx.x * 16;

  float Dsum[3], nwv[3], nbv[3];
#pragma unroll
  for (int i = 0; i < 3; ++i) {
    int d = lane + 64 * i;
    Dsum[i] = Ds[d] + Ds[DD + d] + Ds[2 * DD + d] + Ds[3 * DD + d];
    nwv[i] = nw[d];
    nbv[i] = nb[d];
  }
  const __hip_bfloat16* __restrict__ ysb = ys + (size_t)b * 4 * LL * DD;
  const float* __restrict__ xb = x + (size_t)b * DD * LL;
  float* __restrict__ ob = out + (size_t)b * LL * DD;

  for (int chk = 0; chk < 2; ++chk) {
    const int q0 = p0 + chk * 8;
    float v[8][3];
    float xr[8][3];
#pragma unroll
    for (int i = 0; i < 3; ++i) {
      const float* __restrict__ xrow = xb + (size_t)(lane + 64 * i) * LL + q0;
      float4 x0 = *(const float4*)(xrow);
      float4 x1 = *(const float4*)(xrow + 4);
      xr[0][i]=x0.x; xr[1][i]=x0.y; xr[2][i]=x0.z; xr[3][i]=x0.w;
      xr[4][i]=x1.x; xr[5][i]=x1.y; xr[6][i]=x1.z; xr[7][i]=x1.w;
    }
#pragma unroll
    for (int j = 0; j < 8; ++j) {
      const int pos = q0 + j;
#pragma unroll
      for (int i = 0; i < 3; ++i) {
        const int d = lane + 64 * i;
        const size_t idx = (size_t)pos * DD + d;
        float s = __bfloat162float(ysb[idx])
                + __bfloat162float(ysb[(size_t)LL * DD + idx])
                + __bfloat162float(ysb[(size_t)2 * LL * DD + idx])
                + __bfloat162float(ysb[(size_t)3 * LL * DD + idx]);
        v[j][i] = s + xr[j][i] * Dsum[i];
      }
    }
#pragma unroll
    for (int j = 0; j < 8; ++j) {
      float s1 = v[j][0] + v[j][1] + v[j][2];
      float s2 = v[j][0]*v[j][0] + v[j][1]*v[j][1] + v[j][2]*v[j][2];
#pragma unroll
      for (int m = 1; m < 64; m <<= 1) {
        s1 += __shfl_xor(s1, m);
        s2 += __shfl_xor(s2, m);
      }
      const float mu  = s1 * (1.f / 192.f);
      const float var = s2 * (1.f / 192.f) - mu * mu;
      const float rs  = rsqrtf(var + 1e-5f);
      const int pos = q0 + j;
#pragma unroll
      for (int i = 0; i < 3; ++i) {
        ob[(size_t)pos * DD + lane + 64 * i] = (v[j][i] - mu) * rs * nwv[i] + nbv[i];
      }
    }
  }
}

// ---------------------------------------------------------------------------
// Workspace (fp32 slots), total 30,464,000 slots = 121.9 MB (same as R8):
//   dtr [32][4096][8]    fp32 @ 0           (1,048,576)
//   Bs  [32][4096][16]   fp32 @ 1,048,576   (2,097,152)
//   Cs  [32][4096][16]   fp32 @ 3,145,728   (2,097,152)
//   xh  [8][4096][192]   bf16 @ 5,242,880   (3,145,728 slots)
//   ys  [32][4096][192]  bf16 @ 8,388,608   (12,582,912 slots)
//   P/hin [32][64][192][16] bf16 @ 20,971,520 (3,145,728 slots)
//   q   same             bf16 @ 24,117,248  (3,145,728 slots)
//   xl  [8][4096][192]   bf16 @ 27,262,976  (3,145,728 slots)
//   Whi [192][192]       bf16 @ 30,408,704  (18,432 slots)
//   Wlo [192][192]       bf16 @ 30,427,136  (18,432 slots)
// ---------------------------------------------------------------------------
extern "C" void kernel_launch(void* const* d_in, const int* in_sizes, int n_in,
                              void* d_out, int out_size, void* d_ws, size_t ws_size,
                              hipStream_t stream)
{
  (void)in_sizes; (void)n_in; (void)out_size; (void)ws_size;
  const float* x    = (const float*)d_in[0];
  const float* Wp   = (const float*)d_in[1];
  const float* dtw  = (const float*)d_in[2];
  const float* dtb  = (const float*)d_in[3];
  const float* Alog = (const float*)d_in[4];
  const float* Ds   = (const float*)d_in[5];
  const float* nw   = (const float*)d_in[6];
  const float* nb   = (const float*)d_in[7];
  float* out = (float*)d_out;
  float* ws  = (float*)d_ws;

  float* dtrw = ws;
  float* Bsv  = ws + 1048576;
  float* Csv  = ws + 3145728;
  __hip_bfloat16* xh  = (__hip_bfloat16*)(ws + 5242880);
  __hip_bfloat16* ysv = (__hip_bfloat16*)(ws + 8388608);
  __hip_bfloat16* Pv  = (__hip_bfloat16*)(ws + 20971520);
  __hip_bfloat16* qv  = (__hip_bfloat16*)(ws + 24117248);
  __hip_bfloat16* xlv = (__hip_bfloat16*)(ws + 27262976);
  __hip_bfloat16* Whi = (__hip_bfloat16*)(ws + 30408704);
  __hip_bfloat16* Wlo = (__hip_bfloat16*)(ws + 30427136);

  k_wprep  <<<192, 192, 0, stream>>>(Wp, Whi, Wlo);
  k_xt     <<<dim3(64, 3, 8), 256, 0, stream>>>(x, xh, xlv);
  k_mfproj <<<dim3(256, 8), 192, 0, stream>>>(xh, xlv, Whi, Wlo, dtrw, Bsv, Csv);
  k_partial<<<dim3(32, NCH), DD, 0, stream>>>(dtrw, Bsv, xh, dtw, dtb, Alog, Pv, qv);
  k_comb   <<<384, 256, 0, stream>>>(Pv, qv);
  k_scanc  <<<dim3(32, NCH), DD, 0, stream>>>(dtrw, Bsv, Csv, xh, dtw, dtb, Alog, Pv, ysv);
  k_merge  <<<dim3(256, 8), 64, 0, stream>>>(ysv, x, Ds, nw, nb, out);
}

// Round 10
// 345.879 us; speedup vs baseline: 1.0856x; 1.0856x over previous
//
#include <hip/hip_runtime.h>
#include <hip/hip_bf16.h>

#define LL 4096
#define DD 192
#define NN 16
#define NCH 128     // chunks for the 2-pass scan
#define LC  32      // steps per chunk = LL/NCH

typedef float v2f __attribute__((ext_vector_type(2)));
typedef float f32x4 __attribute__((ext_vector_type(4)));
typedef short bf16x8 __attribute__((ext_vector_type(8)));   // 8 bf16 in 4 VGPRs

__device__ __forceinline__ v2f v2(float a, float b) { v2f r; r.x = a; r.y = b; return r; }
__device__ __forceinline__ float fexp2(float x) { return __builtin_amdgcn_exp2f(x); }

// ---------------------------------------------------------------------------
// K0: weight repack for the MFMA projection (unchanged from R8).
// ---------------------------------------------------------------------------
__global__ __launch_bounds__(192) void k_wprep(
    const float* __restrict__ Wp, __hip_bfloat16* __restrict__ Whi,
    __hip_bfloat16* __restrict__ Wlo)
{
  const int d = threadIdx.x;
  const int r = blockIdx.x;
  const int k = r / 48, cc = r % 48;
  float v = 0.f;
  if      (cc < 6)               v = Wp[((size_t)k * 38 + cc) * DD + d];
  else if (cc >= 8  && cc < 24)  v = Wp[((size_t)k * 38 + 6  + (cc - 8))  * DD + d];
  else if (cc >= 24 && cc < 40)  v = Wp[((size_t)k * 38 + 22 + (cc - 24)) * DD + d];
  const __hip_bfloat16 hi = __float2bfloat16(v);
  Whi[(size_t)r * DD + d] = hi;
  Wlo[(size_t)r * DD + d] = __float2bfloat16(v - __bfloat162float(hi));
}

// ---------------------------------------------------------------------------
// K2: tiled transpose x[b,d,p] -> xh (bf16 hi) + xl (residual) (unchanged).
// ---------------------------------------------------------------------------
__global__ __launch_bounds__(256) void k_xt(
    const float* __restrict__ x, __hip_bfloat16* __restrict__ xh,
    __hip_bfloat16* __restrict__ xl)
{
  __shared__ float tile[64][65];
  const int b = blockIdx.z, d0 = blockIdx.y * 64, p0 = blockIdx.x * 64;
  const int tx = threadIdx.x & 63, ty = threadIdx.x >> 6;
#pragma unroll
  for (int r = ty; r < 64; r += 4)
    tile[r][tx] = x[((size_t)b * DD + d0 + r) * LL + p0 + tx];
  __syncthreads();
#pragma unroll
  for (int pr = ty; pr < 64; pr += 4) {
    const float vv = tile[tx][pr];
    const __hip_bfloat16 hi = __float2bfloat16(vv);
    const size_t idx = ((size_t)b * LL + p0 + pr) * DD + d0 + tx;
    xh[idx] = hi;
    xl[idx] = __float2bfloat16(vv - __bfloat162float(hi));
  }
}

// ---------------------------------------------------------------------------
// K1: MFMA projection (unchanged from R8).
// ---------------------------------------------------------------------------
__global__ __launch_bounds__(192) void k_mfproj(
    const __hip_bfloat16* __restrict__ xh, const __hip_bfloat16* __restrict__ xl,
    const __hip_bfloat16* __restrict__ Whi, const __hip_bfloat16* __restrict__ Wlo,
    float* __restrict__ dtr, float* __restrict__ Bsv, float* __restrict__ Csv)
{
  const int tid  = threadIdx.x;
  const int w    = tid >> 6;          // wave 0..2
  const int lane = tid & 63;
  const int n    = lane & 15;
  const int quad = lane >> 4;
  const int p0   = blockIdx.x * 16;
  const int b    = blockIdx.y;
  const int p    = p0 + n;

  const short* __restrict__ xhp = (const short*)xh + ((size_t)b * LL + p) * DD + quad * 8;
  const short* __restrict__ xlp = (const short*)xl + ((size_t)b * LL + p) * DD + quad * 8;
  const short* __restrict__ whp = (const short*)Whi + ((size_t)(w * 4) * 16 + n) * DD + quad * 8;
  const short* __restrict__ wlp = (const short*)Wlo + ((size_t)(w * 4) * 16 + n) * DD + quad * 8;

  f32x4 acc[4];
#pragma unroll
  for (int m = 0; m < 4; ++m) acc[m] = (f32x4){0.f, 0.f, 0.f, 0.f};

#pragma unroll
  for (int ks = 0; ks < 6; ++ks) {
    const bf16x8 bh = *(const bf16x8*)(xhp + ks * 32);
    const bf16x8 bl = *(const bf16x8*)(xlp + ks * 32);
#pragma unroll
    for (int m = 0; m < 4; ++m) {
      const bf16x8 ah = *(const bf16x8*)(whp + (size_t)m * 16 * DD + ks * 32);
      const bf16x8 al = *(const bf16x8*)(wlp + (size_t)m * 16 * DD + ks * 32);
      acc[m] = __builtin_amdgcn_mfma_f32_16x16x32_bf16(ah, bh, acc[m], 0, 0, 0);
      acc[m] = __builtin_amdgcn_mfma_f32_16x16x32_bf16(ah, bl, acc[m], 0, 0, 0);
      acc[m] = __builtin_amdgcn_mfma_f32_16x16x32_bf16(al, bh, acc[m], 0, 0, 0);
    }
  }

  const int sg = ((p & 63) << 6) | (p >> 6);     // sigma(p)
  int lsv[4] = { p, sg, LL - 1 - p, LL - 1 - sg };

#pragma unroll
  for (int m = 0; m < 4; ++m) {
    const int mt = w * 4 + m;
    const int k  = mt / 3;                        // direction
    const int t  = mt - k * 3;                    // tile within direction
    const int cc0 = t * 16 + quad * 4;            // packed channel of reg 0
    const size_t rowb = (size_t)(b * 4 + k) * LL + lsv[k];
    const float4 vv = make_float4(acc[m][0], acc[m][1], acc[m][2], acc[m][3]);
    if      (cc0 < 8)  *(float4*)(dtr + rowb * 8  + cc0)        = vv;
    else if (cc0 < 24) *(float4*)(Bsv + rowb * 16 + (cc0 - 8))  = vv;
    else if (cc0 < 40) *(float4*)(Csv + rowb * 16 + (cc0 - 24)) = vv;
  }
}

// u-row index for scan position l of direction k.
__device__ __forceinline__ int urow(int l, bool rev, bool trans) {
  const int rl = rev ? (LL - 1 - l) : l;
  return trans ? (((rl & 63) << 6) | (rl >> 6)) : rl;
}

// ---------------------------------------------------------------------------
// K3 (pass A): per-chunk scan summaries. R10: global/s_load memory path
// (R9's LDS staging regressed — reverted). P computed as exp2(An*sum(sp))
// once per chunk (product of exps = exp of sum) -> 8 pk_mul/step removed.
// ---------------------------------------------------------------------------
__global__ __launch_bounds__(192) void k_partial(
    const float* __restrict__ dtr, const float* __restrict__ Bsv,
    const __hip_bfloat16* __restrict__ xt,
    const float* __restrict__ dtw, const float* __restrict__ dtb,
    const float* __restrict__ Alog,
    __hip_bfloat16* __restrict__ Pv, __hip_bfloat16* __restrict__ qv)
{
  const int d  = threadIdx.x;
  const int bk = blockIdx.x;
  const int c  = blockIdx.y;
  const int k = bk & 3, b = bk >> 2;
  const int kd = k * DD + d;
  const bool rev = (k >= 2), trans = (k & 1);
  const float L2E = 1.4426950408889634f;

  v2f An2[8];
#pragma unroll
  for (int j = 0; j < 8; ++j)
    An2[j] = v2(-__expf(Alog[(size_t)kd * NN + 2*j])     * L2E,
                -__expf(Alog[(size_t)kd * NN + 2*j + 1]) * L2E);
  const float w0 = dtw[kd*6+0], w1 = dtw[kd*6+1], w2 = dtw[kd*6+2],
              w3 = dtw[kd*6+3], w4 = dtw[kd*6+4], w5 = dtw[kd*6+5];
  const float bias = dtb[kd];
  const __hip_bfloat16* __restrict__ ub = xt + (size_t)b * LL * DD + d;
  const float* __restrict__ dtrp = dtr + (size_t)bk * LL * 8;
  const float* __restrict__ Bp   = Bsv + (size_t)bk * LL * NN;

  float spsum = 0.f;
  v2f q2[8];
#pragma unroll
  for (int j = 0; j < 8; ++j) q2[j] = v2(0.f, 0.f);

  const int l0 = c * LC;
  float uc = __bfloat162float(ub[(size_t)urow(l0, rev, trans) * DD]);

#pragma unroll 2
  for (int i = 0; i < LC; ++i) {
    const int l = l0 + i;
    float un = 0.f;
    if (i + 1 < LC)
      un = __bfloat162float(ub[(size_t)urow(l + 1, rev, trans) * DD]);
    const float4 r0 = *(const float4*)(dtrp + (size_t)l * 8);
    const float2 r1 = *(const float2*)(dtrp + (size_t)l * 8 + 4);
    const float4 B0 = *(const float4*)(Bp + (size_t)l * NN);
    const float4 B1 = *(const float4*)(Bp + (size_t)l * NN + 4);
    const float4 B2 = *(const float4*)(Bp + (size_t)l * NN + 8);
    const float4 B3 = *(const float4*)(Bp + (size_t)l * NN + 12);
    float v = bias + r0.x*w0 + r0.y*w1 + r0.z*w2 + r0.w*w3 + r1.x*w4 + r1.y*w5;
    const float sp = (v > 20.f) ? v : __logf(1.f + __expf(v));
    const float dbu = sp * uc;
    spsum += sp;
    const v2f sp2  = v2(sp, sp);
    const v2f dbu2 = v2(dbu, dbu);
    const v2f Bv[8] = { v2(B0.x,B0.y), v2(B0.z,B0.w), v2(B1.x,B1.y), v2(B1.z,B1.w),
                        v2(B2.x,B2.y), v2(B2.z,B2.w), v2(B3.x,B3.y), v2(B3.z,B3.w) };
#pragma unroll
    for (int j = 0; j < 8; ++j) {
      const v2f a = sp2 * An2[j];                 // v_pk_mul
      v2f e; e.x = fexp2(a.x); e.y = fexp2(a.y);
      q2[j] = __builtin_elementwise_fma(q2[j], e, dbu2 * Bv[j]);  // pk_mul+pk_fma
    }
    uc = un;
  }

  __hip_bfloat16* __restrict__ Pp = Pv + (((size_t)bk * NCH + c) * DD + d) * NN;
  __hip_bfloat16* __restrict__ qp = qv + (((size_t)bk * NCH + c) * DD + d) * NN;
#pragma unroll
  for (int j = 0; j < 8; ++j) {
    Pp[2*j]   = __float2bfloat16(fexp2(An2[j].x * spsum));
    Pp[2*j+1] = __float2bfloat16(fexp2(An2[j].y * spsum));
    qp[2*j]   = __float2bfloat16(q2[j].x);
    qp[2*j+1] = __float2bfloat16(q2[j].y);
  }
}

// ---------------------------------------------------------------------------
// K4 (pass B): combine chunk summaries; h_in[c] overwrites P[c] in place.
// ---------------------------------------------------------------------------
__global__ __launch_bounds__(256) void k_comb(
    __hip_bfloat16* __restrict__ Pv, const __hip_bfloat16* __restrict__ qv)
{
  const int idx = blockIdx.x * 256 + threadIdx.x;
  const int dn = idx % (DD * NN);
  const int bk = idx / (DD * NN);
  const size_t base = (size_t)bk * NCH * DD * NN + dn;
  float h = 0.f;
  for (int c = 0; c < NCH; ++c) {
    const size_t a = base + (size_t)c * DD * NN;
    const float Pc = __bfloat162float(Pv[a]);
    const float qc = __bfloat162float(qv[a]);
    Pv[a] = __float2bfloat16(h);          // hin[c] = h (pre-chunk state)
    h = fmaf(Pc, h, qc);
  }
}

// ---------------------------------------------------------------------------
// K5 (pass C): real scan per chunk seeded with h_in (global/s_load path,
// reverted from R9's LDS staging; NCH=128 -> 8 waves/SIMD supplied).
// ---------------------------------------------------------------------------
__global__ __launch_bounds__(192) void k_scanc(
    const float* __restrict__ dtr, const float* __restrict__ Bsv,
    const float* __restrict__ Csv, const __hip_bfloat16* __restrict__ xt,
    const float* __restrict__ dtw, const float* __restrict__ dtb,
    const float* __restrict__ Alog, const __hip_bfloat16* __restrict__ hin,
    __hip_bfloat16* __restrict__ ys)
{
  const int d  = threadIdx.x;
  const int bk = blockIdx.x;
  const int c  = blockIdx.y;
  const int k = bk & 3, b = bk >> 2;
  const int kd = k * DD + d;
  const bool rev = (k >= 2), trans = (k & 1);
  const float L2E = 1.4426950408889634f;

  v2f An2[8];
#pragma unroll
  for (int j = 0; j < 8; ++j)
    An2[j] = v2(-__expf(Alog[(size_t)kd * NN + 2*j])     * L2E,
                -__expf(Alog[(size_t)kd * NN + 2*j + 1]) * L2E);
  const float w0 = dtw[kd*6+0], w1 = dtw[kd*6+1], w2 = dtw[kd*6+2],
              w3 = dtw[kd*6+3], w4 = dtw[kd*6+4], w5 = dtw[kd*6+5];
  const float bias = dtb[kd];
  const __hip_bfloat16* __restrict__ ub = xt + (size_t)b * LL * DD + d;
  const float* __restrict__ dtrp = dtr + (size_t)bk * LL * 8;
  const float* __restrict__ Bp   = Bsv + (size_t)bk * LL * NN;
  const float* __restrict__ Cp   = Csv + (size_t)bk * LL * NN;
  __hip_bfloat16* __restrict__ yp = ys + (size_t)bk * LL * DD + d;

  v2f h2[8];
  const __hip_bfloat16* __restrict__ hp = hin + (((size_t)bk * NCH + c) * DD + d) * NN;
#pragma unroll
  for (int j = 0; j < 8; ++j)
    h2[j] = v2(__bfloat162float(hp[2*j]), __bfloat162float(hp[2*j+1]));

  const int l0 = c * LC;
  int rowc = urow(l0, rev, trans);
  float uc = __bfloat162float(ub[(size_t)rowc * DD]);

#pragma unroll 2
  for (int i = 0; i < LC; ++i) {
    const int l = l0 + i;
    int rown = 0; float un = 0.f;
    if (i + 1 < LC) {
      rown = urow(l + 1, rev, trans);
      un = __bfloat162float(ub[(size_t)rown * DD]);
    }
    const float4 r0 = *(const float4*)(dtrp + (size_t)l * 8);
    const float2 r1 = *(const float2*)(dtrp + (size_t)l * 8 + 4);
    const float4 B0 = *(const float4*)(Bp + (size_t)l * NN);
    const float4 B1 = *(const float4*)(Bp + (size_t)l * NN + 4);
    const float4 B2 = *(const float4*)(Bp + (size_t)l * NN + 8);
    const float4 B3 = *(const float4*)(Bp + (size_t)l * NN + 12);
    const float4 C0 = *(const float4*)(Cp + (size_t)l * NN);
    const float4 C1 = *(const float4*)(Cp + (size_t)l * NN + 4);
    const float4 C2 = *(const float4*)(Cp + (size_t)l * NN + 8);
    const float4 C3 = *(const float4*)(Cp + (size_t)l * NN + 12);
    float v = bias + r0.x*w0 + r0.y*w1 + r0.z*w2 + r0.w*w3 + r1.x*w4 + r1.y*w5;
    const float sp = (v > 20.f) ? v : __logf(1.f + __expf(v));
    const float dbu = sp * uc;
    const v2f sp2  = v2(sp, sp);
    const v2f dbu2 = v2(dbu, dbu);
    const v2f Bv[8] = { v2(B0.x,B0.y), v2(B0.z,B0.w), v2(B1.x,B1.y), v2(B1.z,B1.w),
                        v2(B2.x,B2.y), v2(B2.z,B2.w), v2(B3.x,B3.y), v2(B3.z,B3.w) };
    const v2f Cv[8] = { v2(C0.x,C0.y), v2(C0.z,C0.w), v2(C1.x,C1.y), v2(C1.z,C1.w),
                        v2(C2.x,C2.y), v2(C2.z,C2.w), v2(C3.x,C3.y), v2(C3.z,C3.w) };
    v2f ya = v2(0.f, 0.f), yb = v2(0.f, 0.f), yc = v2(0.f, 0.f), yd = v2(0.f, 0.f);
#pragma unroll
    for (int j = 0; j < 8; ++j) {
      const v2f a = sp2 * An2[j];
      v2f e; e.x = fexp2(a.x); e.y = fexp2(a.y);
      h2[j] = __builtin_elementwise_fma(h2[j], e, dbu2 * Bv[j]);
      v2f& yacc = (j < 2) ? ya : (j < 4) ? yb : (j < 6) ? yc : yd;
      yacc = __builtin_elementwise_fma(h2[j], Cv[j], yacc);
    }
    const v2f ysum = (ya + yb) + (yc + yd);
    yp[(size_t)rowc * DD] = __float2bfloat16(ysum.x + ysum.y);
    rowc = rown; uc = un;
  }
}

// ---------------------------------------------------------------------------
// K6: merge + D-skip + LayerNorm(192) + channel-last store. R10: 8 positions
// per 64-thread block (was 16) -> 4096 blocks, 4 waves/SIMD supplied.
// ---------------------------------------------------------------------------
__global__ __launch_bounds__(64) void k_merge(
    const __hip_bfloat16* __restrict__ ys, const float* __restrict__ x,
    const float* __restrict__ Ds, const float* __restrict__ nw,
    const float* __restrict__ nb, float* __restrict__ out)
{
  const int lane = threadIdx.x;
  const int b = blockIdx.y;
  const int q0 = blockIdx.x * 8;

  float Dsum[3], nwv[3], nbv[3];
#pragma unroll
  for (int i = 0; i < 3; ++i) {
    int d = lane + 64 * i;
    Dsum[i] = Ds[d] + Ds[DD + d] + Ds[2 * DD + d] + Ds[3 * DD + d];
    nwv[i] = nw[d];
    nbv[i] = nb[d];
  }
  const __hip_bfloat16* __restrict__ ysb = ys + (size_t)b * 4 * LL * DD;
  const float* __restrict__ xb = x + (size_t)b * DD * LL;
  float* __restrict__ ob = out + (size_t)b * LL * DD;

  float v[8][3];
  float xr[8][3];
#pragma unroll
  for (int i = 0; i < 3; ++i) {
    const float* __restrict__ xrow = xb + (size_t)(lane + 64 * i) * LL + q0;
    float4 x0 = *(const float4*)(xrow);
    float4 x1 = *(const float4*)(xrow + 4);
    xr[0][i]=x0.x; xr[1][i]=x0.y; xr[2][i]=x0.z; xr[3][i]=x0.w;
    xr[4][i]=x1.x; xr[5][i]=x1.y; xr[6][i]=x1.z; xr[7][i]=x1.w;
  }
#pragma unroll
  for (int j = 0; j < 8; ++j) {
    const int pos = q0 + j;
#pragma unroll
    for (int i = 0; i < 3; ++i) {
      const int d = lane + 64 * i;
      const size_t idx = (size_t)pos * DD + d;
      float s = __bfloat162float(ysb[idx])
              + __bfloat162float(ysb[(size_t)LL * DD + idx])
              + __bfloat162float(ysb[(size_t)2 * LL * DD + idx])
              + __bfloat162float(ysb[(size_t)3 * LL * DD + idx]);
      v[j][i] = s + xr[j][i] * Dsum[i];
    }
  }
#pragma unroll
  for (int j = 0; j < 8; ++j) {
    float s1 = v[j][0] + v[j][1] + v[j][2];
    float s2 = v[j][0]*v[j][0] + v[j][1]*v[j][1] + v[j][2]*v[j][2];
#pragma unroll
    for (int m = 1; m < 64; m <<= 1) {
      s1 += __shfl_xor(s1, m);
      s2 += __shfl_xor(s2, m);
    }
    const float mu  = s1 * (1.f / 192.f);
    const float var = s2 * (1.f / 192.f) - mu * mu;
    const float rs  = rsqrtf(var + 1e-5f);
    const int pos = q0 + j;
#pragma unroll
    for (int i = 0; i < 3; ++i) {
      ob[(size_t)pos * DD + lane + 64 * i] = (v[j][i] - mu) * rs * nwv[i] + nbv[i];
    }
  }
}

// ---------------------------------------------------------------------------
// Workspace (fp32 slots), total 27,299,840 slots = 109.2 MB:
//   dtr [32][4096][8]    fp32 @ 0           (1,048,576)
//   Bs  [32][4096][16]   fp32 @ 1,048,576   (2,097,152)
//   Cs  [32][4096][16]   fp32 @ 3,145,728   (2,097,152)
//   xh  [8][4096][192]   bf16 @ 5,242,880   (3,145,728 slots)
//   ys  [32][4096][192]  bf16 @ 8,388,608   (12,582,912 slots)
//     xl [8][4096][192]  bf16 @ 8,388,608   (aliases ys; dead after k_mfproj)
//     q  [32][128][192][16] bf16 @ 11,534,336 (aliases ys; dead after k_comb)
//   P/hin [32][128][192][16] bf16 @ 20,971,520 (6,291,456 slots)
//   Whi [192][192]       bf16 @ 27,262,976  (18,432 slots)
//   Wlo [192][192]       bf16 @ 27,281,408  (18,432 slots)
// ---------------------------------------------------------------------------
extern "C" void kernel_launch(void* const* d_in, const int* in_sizes, int n_in,
                              void* d_out, int out_size, void* d_ws, size_t ws_size,
                              hipStream_t stream)
{
  (void)in_sizes; (void)n_in; (void)out_size; (void)ws_size;
  const float* x    = (const float*)d_in[0];
  const float* Wp   = (const float*)d_in[1];
  const float* dtw  = (const float*)d_in[2];
  const float* dtb  = (const float*)d_in[3];
  const float* Alog = (const float*)d_in[4];
  const float* Ds   = (const float*)d_in[5];
  const float* nw   = (const float*)d_in[6];
  const float* nb   = (const float*)d_in[7];
  float* out = (float*)d_out;
  float* ws  = (float*)d_ws;

  float* dtrw = ws;
  float* Bsv  = ws + 1048576;
  float* Csv  = ws + 3145728;
  __hip_bfloat16* xh  = (__hip_bfloat16*)(ws + 5242880);
  __hip_bfloat16* ysv = (__hip_bfloat16*)(ws + 8388608);
  __hip_bfloat16* xlv = (__hip_bfloat16*)(ws + 8388608);    // alias (dead early)
  __hip_bfloat16* qv  = (__hip_bfloat16*)(ws + 11534336);   // alias (dead early)
  __hip_bfloat16* Pv  = (__hip_bfloat16*)(ws + 20971520);
  __hip_bfloat16* Whi = (__hip_bfloat16*)(ws + 27262976);
  __hip_bfloat16* Wlo = (__hip_bfloat16*)(ws + 27281408);

  k_wprep  <<<192, 192, 0, stream>>>(Wp, Whi, Wlo);
  k_xt     <<<dim3(64, 3, 8), 256, 0, stream>>>(x, xh, xlv);
  k_mfproj <<<dim3(256, 8), 192, 0, stream>>>(xh, xlv, Whi, Wlo, dtrw, Bsv, Csv);
  k_partial<<<dim3(32, NCH), DD, 0, stream>>>(dtrw, Bsv, xh, dtw, dtb, Alog, Pv, qv);
  k_comb   <<<384, 256, 0, stream>>>(Pv, qv);
  k_scanc  <<<dim3(32, NCH), DD, 0, stream>>>(dtrw, Bsv, Csv, xh, dtw, dtb, Alog, Pv, ysv);
  k_merge  <<<dim3(512, 8), 64, 0, stream>>>(ysv, x, Ds, nw, nb, out);
}

// Round 11
// 326.734 us; speedup vs baseline: 1.1492x; 1.0586x over previous
//
#include <hip/hip_runtime.h>
#include <hip/hip_bf16.h>

#define LL 4096
#define DD 192
#define NN 16
#define NCH 128     // chunks for the 2-pass scan
#define LC  32      // steps per chunk = LL/NCH

typedef float v2f __attribute__((ext_vector_type(2)));
typedef float f32x4 __attribute__((ext_vector_type(4)));
typedef short bf16x8 __attribute__((ext_vector_type(8)));   // 8 bf16 in 4 VGPRs

__device__ __forceinline__ v2f v2(float a, float b) { v2f r; r.x = a; r.y = b; return r; }
__device__ __forceinline__ float fexp2(float x) { return __builtin_amdgcn_exp2f(x); }

// ---------------------------------------------------------------------------
// K0: weight repack for the MFMA projection (unchanged from R8).
// ---------------------------------------------------------------------------
__global__ __launch_bounds__(192) void k_wprep(
    const float* __restrict__ Wp, __hip_bfloat16* __restrict__ Whi,
    __hip_bfloat16* __restrict__ Wlo)
{
  const int d = threadIdx.x;
  const int r = blockIdx.x;
  const int k = r / 48, cc = r % 48;
  float v = 0.f;
  if      (cc < 6)               v = Wp[((size_t)k * 38 + cc) * DD + d];
  else if (cc >= 8  && cc < 24)  v = Wp[((size_t)k * 38 + 6  + (cc - 8))  * DD + d];
  else if (cc >= 24 && cc < 40)  v = Wp[((size_t)k * 38 + 22 + (cc - 24)) * DD + d];
  const __hip_bfloat16 hi = __float2bfloat16(v);
  Whi[(size_t)r * DD + d] = hi;
  Wlo[(size_t)r * DD + d] = __float2bfloat16(v - __bfloat162float(hi));
}

// ---------------------------------------------------------------------------
// K0b: A-table precompute. Ant[kd][n] = -exp(Alog)*log2e, fp32 [768][16].
// Removes 16 trans + 16 scalar loads from every scan block (8192 of them).
// ---------------------------------------------------------------------------
__global__ __launch_bounds__(256) void k_an(
    const float* __restrict__ Alog, float* __restrict__ Ant)
{
  const int i = blockIdx.x * 256 + threadIdx.x;   // 12288 total
  Ant[i] = -__expf(Alog[i]) * 1.4426950408889634f;
}

// ---------------------------------------------------------------------------
// K2: tiled transpose x[b,d,p] -> xh (bf16 hi) + xl (residual) (unchanged).
// ---------------------------------------------------------------------------
__global__ __launch_bounds__(256) void k_xt(
    const float* __restrict__ x, __hip_bfloat16* __restrict__ xh,
    __hip_bfloat16* __restrict__ xl)
{
  __shared__ float tile[64][65];
  const int b = blockIdx.z, d0 = blockIdx.y * 64, p0 = blockIdx.x * 64;
  const int tx = threadIdx.x & 63, ty = threadIdx.x >> 6;
#pragma unroll
  for (int r = ty; r < 64; r += 4)
    tile[r][tx] = x[((size_t)b * DD + d0 + r) * LL + p0 + tx];
  __syncthreads();
#pragma unroll
  for (int pr = ty; pr < 64; pr += 4) {
    const float vv = tile[tx][pr];
    const __hip_bfloat16 hi = __float2bfloat16(vv);
    const size_t idx = ((size_t)b * LL + p0 + pr) * DD + d0 + tx;
    xh[idx] = hi;
    xl[idx] = __float2bfloat16(vv - __bfloat162float(hi));
  }
}

// ---------------------------------------------------------------------------
// K1: MFMA projection (unchanged from R8).
// ---------------------------------------------------------------------------
__global__ __launch_bounds__(192) void k_mfproj(
    const __hip_bfloat16* __restrict__ xh, const __hip_bfloat16* __restrict__ xl,
    const __hip_bfloat16* __restrict__ Whi, const __hip_bfloat16* __restrict__ Wlo,
    float* __restrict__ dtr, float* __restrict__ Bsv, float* __restrict__ Csv)
{
  const int tid  = threadIdx.x;
  const int w    = tid >> 6;          // wave 0..2
  const int lane = tid & 63;
  const int n    = lane & 15;
  const int quad = lane >> 4;
  const int p0   = blockIdx.x * 16;
  const int b    = blockIdx.y;
  const int p    = p0 + n;

  const short* __restrict__ xhp = (const short*)xh + ((size_t)b * LL + p) * DD + quad * 8;
  const short* __restrict__ xlp = (const short*)xl + ((size_t)b * LL + p) * DD + quad * 8;
  const short* __restrict__ whp = (const short*)Whi + ((size_t)(w * 4) * 16 + n) * DD + quad * 8;
  const short* __restrict__ wlp = (const short*)Wlo + ((size_t)(w * 4) * 16 + n) * DD + quad * 8;

  f32x4 acc[4];
#pragma unroll
  for (int m = 0; m < 4; ++m) acc[m] = (f32x4){0.f, 0.f, 0.f, 0.f};

#pragma unroll
  for (int ks = 0; ks < 6; ++ks) {
    const bf16x8 bh = *(const bf16x8*)(xhp + ks * 32);
    const bf16x8 bl = *(const bf16x8*)(xlp + ks * 32);
#pragma unroll
    for (int m = 0; m < 4; ++m) {
      const bf16x8 ah = *(const bf16x8*)(whp + (size_t)m * 16 * DD + ks * 32);
      const bf16x8 al = *(const bf16x8*)(wlp + (size_t)m * 16 * DD + ks * 32);
      acc[m] = __builtin_amdgcn_mfma_f32_16x16x32_bf16(ah, bh, acc[m], 0, 0, 0);
      acc[m] = __builtin_amdgcn_mfma_f32_16x16x32_bf16(ah, bl, acc[m], 0, 0, 0);
      acc[m] = __builtin_amdgcn_mfma_f32_16x16x32_bf16(al, bh, acc[m], 0, 0, 0);
    }
  }

  const int sg = ((p & 63) << 6) | (p >> 6);     // sigma(p)
  int lsv[4] = { p, sg, LL - 1 - p, LL - 1 - sg };

#pragma unroll
  for (int m = 0; m < 4; ++m) {
    const int mt = w * 4 + m;
    const int k  = mt / 3;                        // direction
    const int t  = mt - k * 3;                    // tile within direction
    const int cc0 = t * 16 + quad * 4;            // packed channel of reg 0
    const size_t rowb = (size_t)(b * 4 + k) * LL + lsv[k];
    const float4 vv = make_float4(acc[m][0], acc[m][1], acc[m][2], acc[m][3]);
    if      (cc0 < 8)  *(float4*)(dtr + rowb * 8  + cc0)        = vv;
    else if (cc0 < 24) *(float4*)(Bsv + rowb * 16 + (cc0 - 8))  = vv;
    else if (cc0 < 40) *(float4*)(Csv + rowb * 16 + (cc0 - 24)) = vv;
  }
}

// u-row index for scan position l of direction k.
__device__ __forceinline__ int urow(int l, bool rev, bool trans) {
  const int rl = rev ? (LL - 1 - l) : l;
  return trans ? (((rl & 63) << 6) | (rl >> 6)) : rl;
}

// ---------------------------------------------------------------------------
// K3 (pass A): per-chunk scan summaries. R11: An from precomputed table;
// __launch_bounds__(192,6) caps VGPR~85 to lift occupancy (4.4 -> 6 w/SIMD).
// ---------------------------------------------------------------------------
__global__ __launch_bounds__(192, 6) void k_partial(
    const float* __restrict__ dtr, const float* __restrict__ Bsv,
    const __hip_bfloat16* __restrict__ xt, const float* __restrict__ Ant,
    const float* __restrict__ dtw, const float* __restrict__ dtb,
    __hip_bfloat16* __restrict__ Pv, __hip_bfloat16* __restrict__ qv)
{
  const int d  = threadIdx.x;
  const int bk = blockIdx.x;
  const int c  = blockIdx.y;
  const int k = bk & 3, b = bk >> 2;
  const int kd = k * DD + d;
  const bool rev = (k >= 2), trans = (k & 1);

  v2f An2[8];
  {
    const float4* __restrict__ at = (const float4*)(Ant + (size_t)kd * NN);
    const float4 t0 = at[0], t1 = at[1], t2 = at[2], t3 = at[3];
    An2[0]=v2(t0.x,t0.y); An2[1]=v2(t0.z,t0.w);
    An2[2]=v2(t1.x,t1.y); An2[3]=v2(t1.z,t1.w);
    An2[4]=v2(t2.x,t2.y); An2[5]=v2(t2.z,t2.w);
    An2[6]=v2(t3.x,t3.y); An2[7]=v2(t3.z,t3.w);
  }
  const float w0 = dtw[kd*6+0], w1 = dtw[kd*6+1], w2 = dtw[kd*6+2],
              w3 = dtw[kd*6+3], w4 = dtw[kd*6+4], w5 = dtw[kd*6+5];
  const float bias = dtb[kd];
  const __hip_bfloat16* __restrict__ ub = xt + (size_t)b * LL * DD + d;
  const float* __restrict__ dtrp = dtr + (size_t)bk * LL * 8;
  const float* __restrict__ Bp   = Bsv + (size_t)bk * LL * NN;

  float spsum = 0.f;
  v2f q2[8];
#pragma unroll
  for (int j = 0; j < 8; ++j) q2[j] = v2(0.f, 0.f);

  const int l0 = c * LC;
  float uc = __bfloat162float(ub[(size_t)urow(l0, rev, trans) * DD]);

#pragma unroll 2
  for (int i = 0; i < LC; ++i) {
    const int l = l0 + i;
    float un = 0.f;
    if (i + 1 < LC)
      un = __bfloat162float(ub[(size_t)urow(l + 1, rev, trans) * DD]);
    const float4 r0 = *(const float4*)(dtrp + (size_t)l * 8);
    const float2 r1 = *(const float2*)(dtrp + (size_t)l * 8 + 4);
    const float4 B0 = *(const float4*)(Bp + (size_t)l * NN);
    const float4 B1 = *(const float4*)(Bp + (size_t)l * NN + 4);
    const float4 B2 = *(const float4*)(Bp + (size_t)l * NN + 8);
    const float4 B3 = *(const float4*)(Bp + (size_t)l * NN + 12);
    float v = bias + r0.x*w0 + r0.y*w1 + r0.z*w2 + r0.w*w3 + r1.x*w4 + r1.y*w5;
    const float sp = (v > 20.f) ? v : __logf(1.f + __expf(v));
    const float dbu = sp * uc;
    spsum += sp;
    const v2f sp2  = v2(sp, sp);
    const v2f dbu2 = v2(dbu, dbu);
    const v2f Bv[8] = { v2(B0.x,B0.y), v2(B0.z,B0.w), v2(B1.x,B1.y), v2(B1.z,B1.w),
                        v2(B2.x,B2.y), v2(B2.z,B2.w), v2(B3.x,B3.y), v2(B3.z,B3.w) };
#pragma unroll
    for (int j = 0; j < 8; ++j) {
      const v2f a = sp2 * An2[j];                 // v_pk_mul
      v2f e; e.x = fexp2(a.x); e.y = fexp2(a.y);
      q2[j] = __builtin_elementwise_fma(q2[j], e, dbu2 * Bv[j]);  // pk_mul+pk_fma
    }
    uc = un;
  }

  __hip_bfloat16* __restrict__ Pp = Pv + (((size_t)bk * NCH + c) * DD + d) * NN;
  __hip_bfloat16* __restrict__ qp = qv + (((size_t)bk * NCH + c) * DD + d) * NN;
#pragma unroll
  for (int j = 0; j < 8; ++j) {
    Pp[2*j]   = __float2bfloat16(fexp2(An2[j].x * spsum));
    Pp[2*j+1] = __float2bfloat16(fexp2(An2[j].y * spsum));
    qp[2*j]   = __float2bfloat16(q2[j].x);
    qp[2*j+1] = __float2bfloat16(q2[j].y);
  }
}

// ---------------------------------------------------------------------------
// K4 (pass B): combine chunk summaries; h_in[c] overwrites P[c] in place.
// ---------------------------------------------------------------------------
__global__ __launch_bounds__(256) void k_comb(
    __hip_bfloat16* __restrict__ Pv, const __hip_bfloat16* __restrict__ qv)
{
  const int idx = blockIdx.x * 256 + threadIdx.x;
  const int dn = idx % (DD * NN);
  const int bk = idx / (DD * NN);
  const size_t base = (size_t)bk * NCH * DD * NN + dn;
  float h = 0.f;
  for (int c = 0; c < NCH; ++c) {
    const size_t a = base + (size_t)c * DD * NN;
    const float Pc = __bfloat162float(Pv[a]);
    const float qc = __bfloat162float(qv[a]);
    Pv[a] = __float2bfloat16(h);          // hin[c] = h (pre-chunk state)
    h = fmaf(Pc, h, qc);
  }
}

// ---------------------------------------------------------------------------
// K5 (pass C): real scan per chunk seeded with h_in. R11: An table +
// __launch_bounds__(192,6).
// ---------------------------------------------------------------------------
__global__ __launch_bounds__(192, 6) void k_scanc(
    const float* __restrict__ dtr, const float* __restrict__ Bsv,
    const float* __restrict__ Csv, const __hip_bfloat16* __restrict__ xt,
    const float* __restrict__ Ant,
    const float* __restrict__ dtw, const float* __restrict__ dtb,
    const __hip_bfloat16* __restrict__ hin, __hip_bfloat16* __restrict__ ys)
{
  const int d  = threadIdx.x;
  const int bk = blockIdx.x;
  const int c  = blockIdx.y;
  const int k = bk & 3, b = bk >> 2;
  const int kd = k * DD + d;
  const bool rev = (k >= 2), trans = (k & 1);

  v2f An2[8];
  {
    const float4* __restrict__ at = (const float4*)(Ant + (size_t)kd * NN);
    const float4 t0 = at[0], t1 = at[1], t2 = at[2], t3 = at[3];
    An2[0]=v2(t0.x,t0.y); An2[1]=v2(t0.z,t0.w);
    An2[2]=v2(t1.x,t1.y); An2[3]=v2(t1.z,t1.w);
    An2[4]=v2(t2.x,t2.y); An2[5]=v2(t2.z,t2.w);
    An2[6]=v2(t3.x,t3.y); An2[7]=v2(t3.z,t3.w);
  }
  const float w0 = dtw[kd*6+0], w1 = dtw[kd*6+1], w2 = dtw[kd*6+2],
              w3 = dtw[kd*6+3], w4 = dtw[kd*6+4], w5 = dtw[kd*6+5];
  const float bias = dtb[kd];
  const __hip_bfloat16* __restrict__ ub = xt + (size_t)b * LL * DD + d;
  const float* __restrict__ dtrp = dtr + (size_t)bk * LL * 8;
  const float* __restrict__ Bp   = Bsv + (size_t)bk * LL * NN;
  const float* __restrict__ Cp   = Csv + (size_t)bk * LL * NN;
  __hip_bfloat16* __restrict__ yp = ys + (size_t)bk * LL * DD + d;

  v2f h2[8];
  const __hip_bfloat16* __restrict__ hp = hin + (((size_t)bk * NCH + c) * DD + d) * NN;
#pragma unroll
  for (int j = 0; j < 8; ++j)
    h2[j] = v2(__bfloat162float(hp[2*j]), __bfloat162float(hp[2*j+1]));

  const int l0 = c * LC;
  int rowc = urow(l0, rev, trans);
  float uc = __bfloat162float(ub[(size_t)rowc * DD]);

#pragma unroll 2
  for (int i = 0; i < LC; ++i) {
    const int l = l0 + i;
    int rown = 0; float un = 0.f;
    if (i + 1 < LC) {
      rown = urow(l + 1, rev, trans);
      un = __bfloat162float(ub[(size_t)rown * DD]);
    }
    const float4 r0 = *(const float4*)(dtrp + (size_t)l * 8);
    const float2 r1 = *(const float2*)(dtrp + (size_t)l * 8 + 4);
    const float4 B0 = *(const float4*)(Bp + (size_t)l * NN);
    const float4 B1 = *(const float4*)(Bp + (size_t)l * NN + 4);
    const float4 B2 = *(const float4*)(Bp + (size_t)l * NN + 8);
    const float4 B3 = *(const float4*)(Bp + (size_t)l * NN + 12);
    const float4 C0 = *(const float4*)(Cp + (size_t)l * NN);
    const float4 C1 = *(const float4*)(Cp + (size_t)l * NN + 4);
    const float4 C2 = *(const float4*)(Cp + (size_t)l * NN + 8);
    const float4 C3 = *(const float4*)(Cp + (size_t)l * NN + 12);
    float v = bias + r0.x*w0 + r0.y*w1 + r0.z*w2 + r0.w*w3 + r1.x*w4 + r1.y*w5;
    const float sp = (v > 20.f) ? v : __logf(1.f + __expf(v));
    const float dbu = sp * uc;
    const v2f sp2  = v2(sp, sp);
    const v2f dbu2 = v2(dbu, dbu);
    const v2f Bv[8] = { v2(B0.x,B0.y), v2(B0.z,B0.w), v2(B1.x,B1.y), v2(B1.z,B1.w),
                        v2(B2.x,B2.y), v2(B2.z,B2.w), v2(B3.x,B3.y), v2(B3.z,B3.w) };
    const v2f Cv[8] = { v2(C0.x,C0.y), v2(C0.z,C0.w), v2(C1.x,C1.y), v2(C1.z,C1.w),
                        v2(C2.x,C2.y), v2(C2.z,C2.w), v2(C3.x,C3.y), v2(C3.z,C3.w) };
    v2f ya = v2(0.f, 0.f), yb = v2(0.f, 0.f), yc = v2(0.f, 0.f), yd = v2(0.f, 0.f);
#pragma unroll
    for (int j = 0; j < 8; ++j) {
      const v2f a = sp2 * An2[j];
      v2f e; e.x = fexp2(a.x); e.y = fexp2(a.y);
      h2[j] = __builtin_elementwise_fma(h2[j], e, dbu2 * Bv[j]);
      v2f& yacc = (j < 2) ? ya : (j < 4) ? yb : (j < 6) ? yc : yd;
      yacc = __builtin_elementwise_fma(h2[j], Cv[j], yacc);
    }
    const v2f ysum = (ya + yb) + (yc + yd);
    yp[(size_t)rowc * DD] = __float2bfloat16(ysum.x + ysum.y);
    rowc = rown; uc = un;
  }
}

// ---------------------------------------------------------------------------
// K6: merge + D-skip + LayerNorm(192) + channel-last store. R11: x-skip read
// from xh+xl (channel-contiguous bf16 hi/lo ~= fp32 to 2^-17) instead of the
// stride-4096 float4 row gather; every merge load is now coalesced in d.
// ---------------------------------------------------------------------------
__global__ __launch_bounds__(64) void k_merge(
    const __hip_bfloat16* __restrict__ ys,
    const __hip_bfloat16* __restrict__ xh, const __hip_bfloat16* __restrict__ xl,
    const float* __restrict__ Ds, const float* __restrict__ nw,
    const float* __restrict__ nb, float* __restrict__ out)
{
  const int lane = threadIdx.x;
  const int b = blockIdx.y;
  const int q0 = blockIdx.x * 8;

  float Dsum[3], nwv[3], nbv[3];
#pragma unroll
  for (int i = 0; i < 3; ++i) {
    int d = lane + 64 * i;
    Dsum[i] = Ds[d] + Ds[DD + d] + Ds[2 * DD + d] + Ds[3 * DD + d];
    nwv[i] = nw[d];
    nbv[i] = nb[d];
  }
  const __hip_bfloat16* __restrict__ ysb = ys + (size_t)b * 4 * LL * DD;
  const __hip_bfloat16* __restrict__ xhb = xh + (size_t)b * LL * DD;
  const __hip_bfloat16* __restrict__ xlb = xl + (size_t)b * LL * DD;
  float* __restrict__ ob = out + (size_t)b * LL * DD;

  float v[8][3];
#pragma unroll
  for (int j = 0; j < 8; ++j) {
    const int pos = q0 + j;
#pragma unroll
    for (int i = 0; i < 3; ++i) {
      const int d = lane + 64 * i;
      const size_t idx = (size_t)pos * DD + d;
      float s = __bfloat162float(ysb[idx])
              + __bfloat162float(ysb[(size_t)LL * DD + idx])
              + __bfloat162float(ysb[(size_t)2 * LL * DD + idx])
              + __bfloat162float(ysb[(size_t)3 * LL * DD + idx]);
      const float xv = __bfloat162float(xhb[idx]) + __bfloat162float(xlb[idx]);
      v[j][i] = s + xv * Dsum[i];
    }
  }
#pragma unroll
  for (int j = 0; j < 8; ++j) {
    float s1 = v[j][0] + v[j][1] + v[j][2];
    float s2 = v[j][0]*v[j][0] + v[j][1]*v[j][1] + v[j][2]*v[j][2];
#pragma unroll
    for (int m = 1; m < 64; m <<= 1) {
      s1 += __shfl_xor(s1, m);
      s2 += __shfl_xor(s2, m);
    }
    const float mu  = s1 * (1.f / 192.f);
    const float var = s2 * (1.f / 192.f) - mu * mu;
    const float rs  = rsqrtf(var + 1e-5f);
    const int pos = q0 + j;
#pragma unroll
    for (int i = 0; i < 3; ++i) {
      ob[(size_t)pos * DD + lane + 64 * i] = (v[j][i] - mu) * rs * nwv[i] + nbv[i];
    }
  }
}

// ---------------------------------------------------------------------------
// Workspace (fp32 slots), total 30,458,240 slots = 121.8 MB (R8-proven size):
//   dtr [32][4096][8]    fp32 @ 0           (1,048,576)
//   Bs  [32][4096][16]   fp32 @ 1,048,576   (2,097,152)
//   Cs  [32][4096][16]   fp32 @ 3,145,728   (2,097,152)
//   xh  [8][4096][192]   bf16 @ 5,242,880   (3,145,728 slots)
//   ys  [32][4096][192]  bf16 @ 8,388,608   (12,582,912 slots)
//     q  [32][128][192][16] bf16 @ 11,534,336 (aliases ys; dead after k_comb)
//   P/hin [32][128][192][16] bf16 @ 20,971,520 (6,291,456 slots)
//   Whi [192][192]       bf16 @ 27,262,976  (18,432 slots)
//   Wlo [192][192]       bf16 @ 27,281,408  (18,432 slots)
//   xl  [8][4096][192]   bf16 @ 27,299,840  (3,145,728 slots)
//   Ant [768][16]        fp32 @ 30,445,568  (12,288 slots)
// ---------------------------------------------------------------------------
extern "C" void kernel_launch(void* const* d_in, const int* in_sizes, int n_in,
                              void* d_out, int out_size, void* d_ws, size_t ws_size,
                              hipStream_t stream)
{
  (void)in_sizes; (void)n_in; (void)out_size; (void)ws_size;
  const float* x    = (const float*)d_in[0];
  const float* Wp   = (const float*)d_in[1];
  const float* dtw  = (const float*)d_in[2];
  const float* dtb  = (const float*)d_in[3];
  const float* Alog = (const float*)d_in[4];
  const float* Ds   = (const float*)d_in[5];
  const float* nw   = (const float*)d_in[6];
  const float* nb   = (const float*)d_in[7];
  float* out = (float*)d_out;
  float* ws  = (float*)d_ws;

  float* dtrw = ws;
  float* Bsv  = ws + 1048576;
  float* Csv  = ws + 3145728;
  __hip_bfloat16* xh  = (__hip_bfloat16*)(ws + 5242880);
  __hip_bfloat16* ysv = (__hip_bfloat16*)(ws + 8388608);
  __hip_bfloat16* qv  = (__hip_bfloat16*)(ws + 11534336);   // alias (dead early)
  __hip_bfloat16* Pv  = (__hip_bfloat16*)(ws + 20971520);
  __hip_bfloat16* Whi = (__hip_bfloat16*)(ws + 27262976);
  __hip_bfloat16* Wlo = (__hip_bfloat16*)(ws + 27281408);
  __hip_bfloat16* xlv = (__hip_bfloat16*)(ws + 27299840);
  float* Ant          = ws + 30445568;

  k_wprep  <<<192, 192, 0, stream>>>(Wp, Whi, Wlo);
  k_an     <<<48, 256, 0, stream>>>(Alog, Ant);
  k_xt     <<<dim3(64, 3, 8), 256, 0, stream>>>(x, xh, xlv);
  k_mfproj <<<dim3(256, 8), 192, 0, stream>>>(xh, xlv, Whi, Wlo, dtrw, Bsv, Csv);
  k_partial<<<dim3(32, NCH), DD, 0, stream>>>(dtrw, Bsv, xh, Ant, dtw, dtb, Pv, qv);
  k_comb   <<<384, 256, 0, stream>>>(Pv, qv);
  k_scanc  <<<dim3(32, NCH), DD, 0, stream>>>(dtrw, Bsv, Csv, xh, Ant, dtw, dtb, Pv, ysv);
  k_merge  <<<dim3(512, 8), 64, 0, stream>>>(ysv, xh, xlv, Ds, nw, nb, out);
}